// Round 1
// baseline (195.464 us; speedup 1.0000x reference)
//
#include <hip/hip_runtime.h>

#define BM 128
#define BN 128
#define BK 64
#define NSPLIT 8
#define TEMP 0.07f

typedef __attribute__((ext_vector_type(8))) short bf16x8;
typedef __attribute__((ext_vector_type(4))) float f32x4;

__device__ inline short f2bf(float f) {
  unsigned u = __float_as_uint(f);
  u += 0x7fffu + ((u >> 16) & 1u);   // RNE
  return (short)(u >> 16);
}

// L2-normalize rows, fp32 -> bf16(bits in short). One wave per row.
__global__ __launch_bounds__(256) void knorm(const float* __restrict__ X,
                                             short* __restrict__ Fb, int D) {
  int row = blockIdx.x * 4 + (threadIdx.x >> 6);
  int lane = threadIdx.x & 63;
  const float4* xr = (const float4*)(X + (size_t)row * D);
  float4 a = xr[lane * 2];
  float4 b = xr[lane * 2 + 1];
  float ss = a.x*a.x + a.y*a.y + a.z*a.z + a.w*a.w
           + b.x*b.x + b.y*b.y + b.z*b.z + b.w*b.w;
  #pragma unroll
  for (int off = 1; off < 64; off <<= 1) ss += __shfl_xor(ss, off, 64);
  float r = rsqrtf(ss);
  short o[8];
  o[0]=f2bf(a.x*r); o[1]=f2bf(a.y*r); o[2]=f2bf(a.z*r); o[3]=f2bf(a.w*r);
  o[4]=f2bf(b.x*r); o[5]=f2bf(b.y*r); o[6]=f2bf(b.z*r); o[7]=f2bf(b.w*r);
  *(bf16x8*)(Fb + (size_t)row * D + lane * 8) = *(bf16x8*)o;
}

// class histogram (labels in [0,100) per reference; 1024 bins for safety)
__global__ __launch_bounds__(256) void khist(const int* __restrict__ tgt,
                                             int* __restrict__ counts, int N) {
  __shared__ int h[1024];
  for (int i = threadIdx.x; i < 1024; i += 256) h[i] = 0;
  __syncthreads();
  for (int i = threadIdx.x; i < N; i += 256) atomicAdd(&h[tgt[i] & 1023], 1);
  __syncthreads();
  for (int i = threadIdx.x; i < 1024; i += 256) counts[i] = h[i];
}

// Fused sim-tile GEMM + exp/mask row accumulation.
// Block: 128 rows x (N/NSPLIT) cols; 4 waves, each 32 rows x 128 cols per tile.
__global__ __launch_bounds__(256, 2) void kmain(
    const short* __restrict__ F, const int* __restrict__ tgt,
    float* __restrict__ psum, float* __restrict__ pmask, int N, int D) {
  __shared__ short As[BM * BK];
  __shared__ short Bs[BN * BK];

  const int tid  = threadIdx.x;
  const int lane = tid & 63;
  const int wave = tid >> 6;
  const int quad = lane >> 4;
  const int l15  = lane & 15;

  const int rowblk   = blockIdx.x / NSPLIT;
  const int split    = blockIdx.x % NSPLIT;
  const int rowbase  = rowblk * BM;
  const int colbase0 = split * (N / NSPLIT);

  int trow[2][4];
  #pragma unroll
  for (int mi = 0; mi < 2; ++mi)
    #pragma unroll
    for (int r = 0; r < 4; ++r)
      trow[mi][r] = tgt[rowbase + wave*32 + mi*16 + quad*4 + r];

  float se[2][4], ms[2][4];
  #pragma unroll
  for (int mi = 0; mi < 2; ++mi)
    #pragma unroll
    for (int r = 0; r < 4; ++r) { se[mi][r] = 0.f; ms[mi][r] = 0.f; }

  const int sr = tid >> 3;        // staging row within a 32-row group
  const int sc = (tid & 7) * 8;   // staging col (elements)
  const float C1 = (1.0f / TEMP) * 1.4426950408889634f;  // invT*log2(e)
  const float C0 = -C1;

  const int CT = (N / NSPLIT) / BN;
  for (int ct = 0; ct < CT; ++ct) {
    const int colbase = colbase0 + ct * BN;

    f32x4 acc[2][8];
    #pragma unroll
    for (int mi = 0; mi < 2; ++mi)
      #pragma unroll
      for (int ni = 0; ni < 8; ++ni)
        acc[mi][ni] = (f32x4){0.f, 0.f, 0.f, 0.f};

    for (int kb = 0; kb < D; kb += BK) {
      __syncthreads();
      #pragma unroll
      for (int it = 0; it < 4; ++it) {
        const int r = it * 32 + sr;
        const short* gA = F + (size_t)(rowbase + r) * D + kb + sc;
        const short* gB = F + (size_t)(colbase + r) * D + kb + sc;
        short* lA = As + (it * 256 + tid) * 8;
        short* lB = Bs + (it * 256 + tid) * 8;
        __builtin_amdgcn_global_load_lds(
            (const __attribute__((address_space(1))) void*)gA,
            (__attribute__((address_space(3))) void*)lA, 16, 0, 0);
        __builtin_amdgcn_global_load_lds(
            (const __attribute__((address_space(1))) void*)gB,
            (__attribute__((address_space(3))) void*)lB, 16, 0, 0);
      }
      __syncthreads();

      #pragma unroll
      for (int kk = 0; kk < BK; kk += 32) {
        bf16x8 a0 = *(const bf16x8*)&As[(wave*32 + 0  + l15)*BK + kk + quad*8];
        bf16x8 a1 = *(const bf16x8*)&As[(wave*32 + 16 + l15)*BK + kk + quad*8];
        #pragma unroll
        for (int ni = 0; ni < 8; ++ni) {
          bf16x8 b = *(const bf16x8*)&Bs[(ni*16 + l15)*BK + kk + quad*8];
          acc[0][ni] = __builtin_amdgcn_mfma_f32_16x16x32_bf16(a0, b, acc[0][ni], 0, 0, 0);
          acc[1][ni] = __builtin_amdgcn_mfma_f32_16x16x32_bf16(a1, b, acc[1][ni], 0, 0, 0);
        }
      }
    }

    // epilogue: fold the 32x128 tile into per-row partial sums
    int tc[8];
    #pragma unroll
    for (int ni = 0; ni < 8; ++ni) tc[ni] = tgt[colbase + ni*16 + l15];
    #pragma unroll
    for (int mi = 0; mi < 2; ++mi)
      #pragma unroll
      for (int ni = 0; ni < 8; ++ni)
        #pragma unroll
        for (int r = 0; r < 4; ++r) {
          float v = acc[mi][ni][r];                 // raw dot in [-1,1]
          se[mi][r] += __builtin_amdgcn_exp2f(fmaf(v, C1, C0));
          if (tc[ni] == trow[mi][r]) ms[mi][r] += v;  // diagonal removed later
        }
  }

  // reduce across the 16 lanes of each quad (cols), write per-row partials
  #pragma unroll
  for (int mi = 0; mi < 2; ++mi)
    #pragma unroll
    for (int r = 0; r < 4; ++r) {
      float s = se[mi][r], m = ms[mi][r];
      #pragma unroll
      for (int off = 1; off < 16; off <<= 1) {
        s += __shfl_xor(s, off, 64);
        m += __shfl_xor(m, off, 64);
      }
      if (l15 == 0) {
        int row = rowbase + wave*32 + mi*16 + quad*4 + r;
        psum[(size_t)split * N + row]  = s;
        pmask[(size_t)split * N + row] = m;
      }
    }
}

// finalize: per-row term, global mean, negate.
__global__ __launch_bounds__(256) void kfinal(
    const float* __restrict__ psum, const float* __restrict__ pmask,
    const int* __restrict__ tgt, const int* __restrict__ counts,
    float* __restrict__ out, int N) {
  int i = blockIdx.x * 256 + threadIdx.x;
  float s = 0.f, m = 0.f;
  #pragma unroll
  for (int sp = 0; sp < NSPLIT; ++sp) {
    s += psum[(size_t)sp * N + i];
    m += pmask[(size_t)sp * N + i];
  }
  const float invT = 1.0f / TEMP;
  float cnt = (float)(counts[tgt[i] & 1023] - 1);
  // LSE_i = invT + log(s);  sum_mask sim = (m - selfdot(~1.0)) * invT
  float term = (m - 1.0f) * invT / cnt - (logf(s) + invT);
  #pragma unroll
  for (int off = 1; off < 64; off <<= 1) term += __shfl_xor(term, off, 64);
  __shared__ float wsum[4];
  if ((threadIdx.x & 63) == 0) wsum[threadIdx.x >> 6] = term;
  __syncthreads();
  if (threadIdx.x == 0)
    atomicAdd(out, -(wsum[0] + wsum[1] + wsum[2] + wsum[3]) / (float)N);
}

extern "C" void kernel_launch(void* const* d_in, const int* in_sizes, int n_in,
                              void* d_out, int out_size, void* d_ws, size_t ws_size,
                              hipStream_t stream) {
  const float* X  = (const float*)d_in[0];
  const int* tgt  = (const int*)d_in[1];
  float* out      = (float*)d_out;
  const int N = in_sizes[1];
  const int D = in_sizes[0] / N;

  char* w = (char*)d_ws;
  short* Fb = (short*)w;
  size_t off = (size_t)N * D * sizeof(short);
  float* psum  = (float*)(w + off); off += (size_t)NSPLIT * N * sizeof(float);
  float* pmask = (float*)(w + off); off += (size_t)NSPLIT * N * sizeof(float);
  int* counts  = (int*)(w + off);

  hipMemsetAsync(d_out, 0, sizeof(float), stream);
  knorm<<<N / 4, 256, 0, stream>>>(X, Fb, D);
  khist<<<1, 256, 0, stream>>>(tgt, counts, N);
  kmain<<<(N / BM) * NSPLIT, 256, 0, stream>>>(Fb, tgt, psum, pmask, N, D);
  kfinal<<<N / 256, 256, 0, stream>>>(psum, pmask, tgt, counts, out, N);
}

// Round 2
// 179.519 us; speedup vs baseline: 1.0888x; 1.0888x over previous
//
#include <hip/hip_runtime.h>

#define BM 128
#define BN 128
#define NSPLIT 8
#define TEMP 0.07f

typedef __attribute__((ext_vector_type(8))) short bf16x8;
typedef __attribute__((ext_vector_type(4))) float f32x4;

__device__ inline short f2bf(float f) {
  unsigned u = __float_as_uint(f);
  u += 0x7fffu + ((u >> 16) & 1u);   // RNE
  return (short)(u >> 16);
}

// L2-normalize rows, fp32 -> bf16(bits in short). One wave per row.
__global__ __launch_bounds__(256) void knorm(const float* __restrict__ X,
                                             short* __restrict__ Fb, int D) {
  int row = blockIdx.x * 4 + (threadIdx.x >> 6);
  int lane = threadIdx.x & 63;
  const float4* xr = (const float4*)(X + (size_t)row * D);
  float4 a = xr[lane * 2];
  float4 b = xr[lane * 2 + 1];
  float ss = a.x*a.x + a.y*a.y + a.z*a.z + a.w*a.w
           + b.x*b.x + b.y*b.y + b.z*b.z + b.w*b.w;
  #pragma unroll
  for (int off = 1; off < 64; off <<= 1) ss += __shfl_xor(ss, off, 64);
  float r = rsqrtf(ss);
  short o[8];
  o[0]=f2bf(a.x*r); o[1]=f2bf(a.y*r); o[2]=f2bf(a.z*r); o[3]=f2bf(a.w*r);
  o[4]=f2bf(b.x*r); o[5]=f2bf(b.y*r); o[6]=f2bf(b.z*r); o[7]=f2bf(b.w*r);
  *(bf16x8*)(Fb + (size_t)row * D + lane * 8) = *(bf16x8*)o;
}

// Fused sim-tile GEMM + exp/mask row accumulation.
// A held entirely in registers (32 rows x 512 k per wave = 128 VGPRs).
// B staged through 64 KB LDS with XOR-swizzled 16B slots (no bank conflicts).
__global__ __launch_bounds__(256, 2) void kmain(
    const short* __restrict__ F, const int* __restrict__ tgt,
    float* __restrict__ psum, float* __restrict__ pmask, int N, int D) {
  __shared__ short Bs[BN * 256];   // 128 rows x 256 k = 64 KB

  const int tid  = threadIdx.x;
  const int lane = tid & 63;
  const int wave = tid >> 6;
  const int quad = lane >> 4;
  const int l15  = lane & 15;
  const int l7   = l15 & 7;

  const int rowblk   = blockIdx.x / NSPLIT;
  const int split    = blockIdx.x % NSPLIT;
  const int rowbase  = rowblk * BM;
  const int colbase0 = split * (N / NSPLIT);

  // ---- A fragments: 2 mi x 16 k-chunks, loaded once ----
  bf16x8 af[2][16];
  #pragma unroll
  for (int mi = 0; mi < 2; ++mi) {
    const short* rp = F + (size_t)(rowbase + wave*32 + mi*16 + l15) * D + quad*8;
    #pragma unroll
    for (int kc = 0; kc < 16; ++kc)
      af[mi][kc] = *(const bf16x8*)(rp + kc * 32);
  }

  int trow[2][4];
  #pragma unroll
  for (int mi = 0; mi < 2; ++mi)
    #pragma unroll
    for (int r = 0; r < 4; ++r)
      trow[mi][r] = tgt[rowbase + wave*32 + mi*16 + quad*4 + r];

  float se[2][4], ms[2][4];
  #pragma unroll
  for (int mi = 0; mi < 2; ++mi)
    #pragma unroll
    for (int r = 0; r < 4; ++r) { se[mi][r] = 0.f; ms[mi][r] = 0.f; }

  const float C1 = (1.0f / TEMP) * 1.4426950408889634f;  // invT*log2(e)
  const float C0 = -C1;

  const int CT = (N / NSPLIT) / BN;   // 8
  for (int ct = 0; ct < CT; ++ct) {
    const int colbase = colbase0 + ct * BN;

    f32x4 acc[2][8];
    #pragma unroll
    for (int mi = 0; mi < 2; ++mi)
      #pragma unroll
      for (int ni = 0; ni < 8; ++ni)
        acc[mi][ni] = (f32x4){0.f, 0.f, 0.f, 0.f};

    #pragma unroll
    for (int kbi = 0; kbi < 2; ++kbi) {       // two 256-wide K halves
      __syncthreads();
      // stage B half-tile: 128 rows x 256 k, swizzled slot = sp, logical = sp^(row&7)
      #pragma unroll
      for (int it = 0; it < 16; ++it) {
        const int L   = it * 256 + tid;       // 16B-slot linear index
        const int row = L >> 5;               // 32 slots per row
        const int sp  = L & 31;
        const int sl  = sp ^ (row & 7);
        const short* g = F + (size_t)(colbase + row) * D + kbi*256 + sl*8;
        short* l = Bs + L * 8;
        __builtin_amdgcn_global_load_lds(
            (const __attribute__((address_space(1))) void*)g,
            (__attribute__((address_space(3))) void*)l, 16, 0, 0);
      }
      __syncthreads();

      #pragma unroll
      for (int kk = 0; kk < 8; ++kk) {
        #pragma unroll
        for (int ni = 0; ni < 8; ++ni) {
          bf16x8 b = *(const bf16x8*)
              &Bs[(ni*16 + l15)*256 + (((kk*4 + quad) ^ l7) * 8)];
          acc[0][ni] = __builtin_amdgcn_mfma_f32_16x16x32_bf16(af[0][kbi*8+kk], b, acc[0][ni], 0, 0, 0);
          acc[1][ni] = __builtin_amdgcn_mfma_f32_16x16x32_bf16(af[1][kbi*8+kk], b, acc[1][ni], 0, 0, 0);
        }
      }
    }

    // epilogue: fold the 32x128 tile into per-row partial sums
    int tc[8];
    #pragma unroll
    for (int ni = 0; ni < 8; ++ni) tc[ni] = tgt[colbase + ni*16 + l15];
    #pragma unroll
    for (int mi = 0; mi < 2; ++mi)
      #pragma unroll
      for (int ni = 0; ni < 8; ++ni)
        #pragma unroll
        for (int r = 0; r < 4; ++r) {
          float v = acc[mi][ni][r];                 // raw dot in [-1,1]
          se[mi][r] += __builtin_amdgcn_exp2f(fmaf(v, C1, C0));
          if (tc[ni] == trow[mi][r]) ms[mi][r] += v;  // diagonal removed later
        }
  }

  // reduce across the 16 lanes of each quad (cols), write per-row partials
  #pragma unroll
  for (int mi = 0; mi < 2; ++mi)
    #pragma unroll
    for (int r = 0; r < 4; ++r) {
      float s = se[mi][r], m = ms[mi][r];
      #pragma unroll
      for (int off = 1; off < 16; off <<= 1) {
        s += __shfl_xor(s, off, 64);
        m += __shfl_xor(m, off, 64);
      }
      if (l15 == 0) {
        int row = rowbase + wave*32 + mi*16 + quad*4 + r;
        psum[(size_t)split * N + row]  = s;
        pmask[(size_t)split * N + row] = m;
      }
    }
}

// finalize: histogram labels, per-row term, global mean, negate.
__global__ __launch_bounds__(256) void kfinal(
    const float* __restrict__ psum, const float* __restrict__ pmask,
    const int* __restrict__ tgt, float* __restrict__ out, int N) {
  __shared__ int h[128];
  for (int i = threadIdx.x; i < 128; i += 256) h[i] = 0;
  __syncthreads();
  for (int i = threadIdx.x; i < N; i += 256) atomicAdd(&h[tgt[i] & 127], 1);
  __syncthreads();

  int i = blockIdx.x * 256 + threadIdx.x;
  float s = 0.f, m = 0.f;
  #pragma unroll
  for (int sp = 0; sp < NSPLIT; ++sp) {
    s += psum[(size_t)sp * N + i];
    m += pmask[(size_t)sp * N + i];
  }
  const float invT = 1.0f / TEMP;
  float cnt = (float)(h[tgt[i] & 127] - 1);
  // LSE_i = invT + log(s);  sum_mask sim = (m - selfdot(~1.0)) * invT
  float term = (m - 1.0f) * invT / cnt - (logf(s) + invT);
  #pragma unroll
  for (int off = 1; off < 64; off <<= 1) term += __shfl_xor(term, off, 64);
  __shared__ float wsum[4];
  if ((threadIdx.x & 63) == 0) wsum[threadIdx.x >> 6] = term;
  __syncthreads();
  if (threadIdx.x == 0)
    atomicAdd(out, -(wsum[0] + wsum[1] + wsum[2] + wsum[3]) / (float)N);
}

extern "C" void kernel_launch(void* const* d_in, const int* in_sizes, int n_in,
                              void* d_out, int out_size, void* d_ws, size_t ws_size,
                              hipStream_t stream) {
  const float* X  = (const float*)d_in[0];
  const int* tgt  = (const int*)d_in[1];
  float* out      = (float*)d_out;
  const int N = in_sizes[1];
  const int D = in_sizes[0] / N;

  char* w = (char*)d_ws;
  short* Fb = (short*)w;
  size_t off = (size_t)N * D * sizeof(short);
  float* psum  = (float*)(w + off); off += (size_t)NSPLIT * N * sizeof(float);
  float* pmask = (float*)(w + off);

  hipMemsetAsync(d_out, 0, sizeof(float), stream);
  knorm<<<N / 4, 256, 0, stream>>>(X, Fb, D);
  kmain<<<(N / BM) * NSPLIT, 256, 0, stream>>>(Fb, tgt, psum, pmask, N, D);
  kfinal<<<N / 256, 256, 0, stream>>>(psum, pmask, tgt, out, N);
}

// Round 3
// 154.820 us; speedup vs baseline: 1.2625x; 1.1595x over previous
//
#include <hip/hip_runtime.h>

#define BM 128
#define BN 128
#define NSPLIT 8
#define TEMP 0.07f

typedef __attribute__((ext_vector_type(4))) float f32x4;

// L2-normalize rows of X (fp32, N x 512), emit fp8 e4m3 (1 B/elem). One wave/row.
__global__ __launch_bounds__(256) void knorm(const float* __restrict__ X,
                                             unsigned char* __restrict__ Fq, int D) {
  int row = blockIdx.x * 4 + (threadIdx.x >> 6);
  int lane = threadIdx.x & 63;
  const float4* xr = (const float4*)(X + (size_t)row * D);
  float4 a = xr[lane * 2];
  float4 b = xr[lane * 2 + 1];
  float ss = a.x*a.x + a.y*a.y + a.z*a.z + a.w*a.w
           + b.x*b.x + b.y*b.y + b.z*b.z + b.w*b.w;
  #pragma unroll
  for (int off = 1; off < 64; off <<= 1) ss += __shfl_xor(ss, off, 64);
  float r = rsqrtf(ss);
  int lo = 0, hi = 0;
  lo = __builtin_amdgcn_cvt_pk_fp8_f32(a.x*r, a.y*r, lo, false);
  lo = __builtin_amdgcn_cvt_pk_fp8_f32(a.z*r, a.w*r, lo, true);
  hi = __builtin_amdgcn_cvt_pk_fp8_f32(b.x*r, b.y*r, hi, false);
  hi = __builtin_amdgcn_cvt_pk_fp8_f32(b.z*r, b.w*r, hi, true);
  int2 o = make_int2(lo, hi);
  *(int2*)(Fq + (size_t)row * D + lane * 8) = o;
}

// Fused sim-tile GEMM + exp/mask row accumulation, fp8 e4m3 inputs.
// A resident in registers: 32 rows x 512 k per wave = 64 VGPRs (fp8).
// B staged through 64 KB LDS (full K=512), 16B slots XOR-swizzled by row.
// amdgpu_waves_per_eu(2,2): force 256-VGPR budget so af/acc never spill (R2 lesson).
__global__ __launch_bounds__(256)
__attribute__((amdgpu_waves_per_eu(2, 2)))
void kmain(const unsigned char* __restrict__ F, const int* __restrict__ tgt,
           float* __restrict__ psum, float* __restrict__ pmask, int N, int D) {
  __shared__ __align__(16) unsigned char Bs[BN * 512];   // 128 rows x 512 B = 64 KB

  const int tid  = threadIdx.x;
  const int lane = tid & 63;
  const int wave = tid >> 6;
  const int quad = lane >> 4;
  const int l15  = lane & 15;

  const int rowblk   = blockIdx.x / NSPLIT;
  const int split    = blockIdx.x % NSPLIT;   // aligns with XCD round-robin -> L2 reuse
  const int rowbase  = rowblk * BM;
  const int colbase0 = split * (N / NSPLIT);

  // ---- A fragments, loaded once: 2 mi x 16 ksteps x 8 fp8 ----
  long af[2][16];
  #pragma unroll
  for (int mi = 0; mi < 2; ++mi) {
    const unsigned char* rp = F + (size_t)(rowbase + wave*32 + mi*16 + l15) * 512 + quad*8;
    #pragma unroll
    for (int k = 0; k < 16; ++k)
      af[mi][k] = *(const long*)(rp + k * 32);
  }

  int trow[2][4];
  #pragma unroll
  for (int mi = 0; mi < 2; ++mi)
    #pragma unroll
    for (int r = 0; r < 4; ++r)
      trow[mi][r] = tgt[rowbase + wave*32 + mi*16 + quad*4 + r];

  float se[2][4], ms[2][4];
  #pragma unroll
  for (int mi = 0; mi < 2; ++mi)
    #pragma unroll
    for (int r = 0; r < 4; ++r) { se[mi][r] = 0.f; ms[mi][r] = 0.f; }

  const float C1 = (1.0f / TEMP) * 1.4426950408889634f;  // invT*log2(e)
  const float C0 = -C1;

  const int CT = (N / NSPLIT) / BN;   // 8
  for (int ct = 0; ct < CT; ++ct) {
    const int colbase = colbase0 + ct * BN;

    f32x4 acc[2][8];
    #pragma unroll
    for (int mi = 0; mi < 2; ++mi)
      #pragma unroll
      for (int ni = 0; ni < 8; ++ni)
        acc[mi][ni] = (f32x4){0.f, 0.f, 0.f, 0.f};

    __syncthreads();
    // stage B tile (128 rows x 512 B). phys 16B-slot p holds logical kslot p^(row&31).
    #pragma unroll
    for (int it = 0; it < 16; ++it) {
      const int L   = it * 256 + tid;   // phys 16B-slot linear index
      const int row = L >> 5;           // 32 slots per row
      const int ks  = (L & 31) ^ (row & 31);
      const unsigned char* g = F + (size_t)(colbase + row) * 512 + ks * 16;
      __builtin_amdgcn_global_load_lds(
          (const __attribute__((address_space(1))) void*)g,
          (__attribute__((address_space(3))) void*)(Bs + L * 16), 16, 0, 0);
    }
    __syncthreads();

    #pragma unroll
    for (int k = 0; k < 16; ++k) {
      #pragma unroll
      for (int ni = 0; ni < 8; ++ni) {
        const int row = ni*16 + l15;
        const int g8  = k*4 + quad;                       // 8-byte group in row
        const int a   = row*512 + (((g8 >> 1) ^ (row & 31)) << 4) + (g8 & 1)*8;
        long b = *(const long*)(Bs + a);
        acc[0][ni] = __builtin_amdgcn_mfma_f32_16x16x32_fp8_fp8(af[0][k], b, acc[0][ni], 0, 0, 0);
        acc[1][ni] = __builtin_amdgcn_mfma_f32_16x16x32_fp8_fp8(af[1][k], b, acc[1][ni], 0, 0, 0);
      }
    }

    // epilogue: fold the 32x128 tile into per-row partial sums
    int tc[8];
    #pragma unroll
    for (int ni = 0; ni < 8; ++ni) tc[ni] = tgt[colbase + ni*16 + l15];
    #pragma unroll
    for (int mi = 0; mi < 2; ++mi)
      #pragma unroll
      for (int ni = 0; ni < 8; ++ni)
        #pragma unroll
        for (int r = 0; r < 4; ++r) {
          float v = acc[mi][ni][r];                 // raw dot in [-1,1]
          se[mi][r] += __builtin_amdgcn_exp2f(fmaf(v, C1, C0));
          if (tc[ni] == trow[mi][r]) ms[mi][r] += v;  // diagonal removed in kfinal
        }
  }

  // reduce across the 16 lanes of each quad (cols), write per-row partials
  #pragma unroll
  for (int mi = 0; mi < 2; ++mi)
    #pragma unroll
    for (int r = 0; r < 4; ++r) {
      float s = se[mi][r], m = ms[mi][r];
      #pragma unroll
      for (int off = 1; off < 16; off <<= 1) {
        s += __shfl_xor(s, off, 64);
        m += __shfl_xor(m, off, 64);
      }
      if (l15 == 0) {
        int row = rowbase + wave*32 + mi*16 + quad*4 + r;
        psum[(size_t)split * N + row]  = s;
        pmask[(size_t)split * N + row] = m;
      }
    }
}

// finalize (single block, writes out directly — no memset node needed):
// histogram labels, per-row term, global mean, negate.
__global__ __launch_bounds__(1024) void kfinal(
    const float* __restrict__ psum, const float* __restrict__ pmask,
    const int* __restrict__ tgt, float* __restrict__ out, int N) {
  __shared__ int h[128];
  __shared__ float wsum[16];
  const int tid = threadIdx.x;
  if (tid < 128) h[tid] = 0;
  __syncthreads();
  for (int i = tid; i < N; i += 1024) atomicAdd(&h[tgt[i] & 127], 1);
  __syncthreads();

  const float invT = 1.0f / TEMP;
  float local = 0.f;
  for (int i = tid; i < N; i += 1024) {
    float s = 0.f, m = 0.f;
    #pragma unroll
    for (int sp = 0; sp < NSPLIT; ++sp) {
      s += psum[(size_t)sp * N + i];
      m += pmask[(size_t)sp * N + i];
    }
    float cnt = (float)(h[tgt[i] & 127] - 1);
    // LSE_i = invT + log(s);  sum_mask sim = (m - selfdot(~1.0)) * invT
    local += (m - 1.0f) * invT / cnt - (logf(s) + invT);
  }
  #pragma unroll
  for (int off = 1; off < 64; off <<= 1) local += __shfl_xor(local, off, 64);
  if ((tid & 63) == 0) wsum[tid >> 6] = local;
  __syncthreads();
  if (tid == 0) {
    float t = 0.f;
    #pragma unroll
    for (int w = 0; w < 16; ++w) t += wsum[w];
    out[0] = -t / (float)N;
  }
}

extern "C" void kernel_launch(void* const* d_in, const int* in_sizes, int n_in,
                              void* d_out, int out_size, void* d_ws, size_t ws_size,
                              hipStream_t stream) {
  const float* X  = (const float*)d_in[0];
  const int* tgt  = (const int*)d_in[1];
  float* out      = (float*)d_out;
  const int N = in_sizes[1];
  const int D = in_sizes[0] / N;

  char* w = (char*)d_ws;
  unsigned char* Fq = (unsigned char*)w;
  size_t off = (size_t)N * D;                          // fp8: 1 B/elem
  float* psum  = (float*)(w + off); off += (size_t)NSPLIT * N * sizeof(float);
  float* pmask = (float*)(w + off);

  knorm<<<N / 4, 256, 0, stream>>>(X, Fq, D);
  kmain<<<(N / BM) * NSPLIT, 256, 0, stream>>>(Fq, tgt, psum, pmask, N, D);
  kfinal<<<1, 1024, 0, stream>>>(psum, pmask, tgt, out, N);
}

// Round 4
// 143.310 us; speedup vs baseline: 1.3639x; 1.0803x over previous
//
#include <hip/hip_runtime.h>

#define BM 128
#define BN 128
#define NSPLIT 8
#define TEMP 0.07f

typedef __attribute__((ext_vector_type(4))) float f32x4;

// L2-normalize rows of X (fp32, N x 512), emit fp8 e4m3 (1 B/elem). One wave/row.
__global__ __launch_bounds__(256) void knorm(const float* __restrict__ X,
                                             unsigned char* __restrict__ Fq, int D) {
  int row = blockIdx.x * 4 + (threadIdx.x >> 6);
  int lane = threadIdx.x & 63;
  const float4* xr = (const float4*)(X + (size_t)row * D);
  float4 a = xr[lane * 2];
  float4 b = xr[lane * 2 + 1];
  float ss = a.x*a.x + a.y*a.y + a.z*a.z + a.w*a.w
           + b.x*b.x + b.y*b.y + b.z*b.z + b.w*b.w;
  #pragma unroll
  for (int off = 1; off < 64; off <<= 1) ss += __shfl_xor(ss, off, 64);
  float r = rsqrtf(ss);
  int lo = 0, hi = 0;
  lo = __builtin_amdgcn_cvt_pk_fp8_f32(a.x*r, a.y*r, lo, false);
  lo = __builtin_amdgcn_cvt_pk_fp8_f32(a.z*r, a.w*r, lo, true);
  hi = __builtin_amdgcn_cvt_pk_fp8_f32(b.x*r, b.y*r, hi, false);
  hi = __builtin_amdgcn_cvt_pk_fp8_f32(b.z*r, b.w*r, hi, true);
  int2 o = make_int2(lo, hi);
  *(int2*)(Fq + (size_t)row * D + lane * 8) = o;
}

// Fused sim-tile GEMM + exp/mask row accumulation, fp8 e4m3 inputs.
// A resident in registers: 32 rows x 512 k per wave = 64 VGPRs (fp8).
// B staged through 64 KB LDS (full K=512), 16B slots XOR-swizzled by row.
// __launch_bounds__(256,1): min 1 wave/EU -> up to 512-VGPR budget. The
// R2/R3 spills came from the allocator capping at 128; LDS (64KB) limits
// us to 2 blocks/CU regardless, so the relaxed bound costs no occupancy.
__global__ __launch_bounds__(256, 1)
void kmain(const unsigned char* __restrict__ F, const int* __restrict__ tgt,
           float* __restrict__ psum, float* __restrict__ pmask, int N, int D) {
  __shared__ __align__(16) unsigned char Bs[BN * 512];   // 128 rows x 512 B = 64 KB

  const int tid  = threadIdx.x;
  const int lane = tid & 63;
  const int wave = tid >> 6;
  const int quad = lane >> 4;
  const int l15  = lane & 15;

  const int rowblk   = blockIdx.x / NSPLIT;
  const int split    = blockIdx.x % NSPLIT;   // aligns with XCD round-robin -> L2 reuse
  const int rowbase  = rowblk * BM;
  const int colbase0 = split * (N / NSPLIT);

  // ---- A fragments, loaded once: 2 mi x 16 ksteps x 8 fp8 ----
  long af[2][16];
  #pragma unroll
  for (int mi = 0; mi < 2; ++mi) {
    const unsigned char* rp = F + (size_t)(rowbase + wave*32 + mi*16 + l15) * 512 + quad*8;
    #pragma unroll
    for (int k = 0; k < 16; ++k)
      af[mi][k] = *(const long*)(rp + k * 32);
  }

  int trow[2][4];
  #pragma unroll
  for (int mi = 0; mi < 2; ++mi)
    #pragma unroll
    for (int r = 0; r < 4; ++r)
      trow[mi][r] = tgt[rowbase + wave*32 + mi*16 + quad*4 + r];

  float se[2][4], ms[2][4];
  #pragma unroll
  for (int mi = 0; mi < 2; ++mi)
    #pragma unroll
    for (int r = 0; r < 4; ++r) { se[mi][r] = 0.f; ms[mi][r] = 0.f; }

  const float C1 = (1.0f / TEMP) * 1.4426950408889634f;  // invT*log2(e)
  const float C0 = -C1;

  const int CT = (N / NSPLIT) / BN;   // 8
  for (int ct = 0; ct < CT; ++ct) {
    const int colbase = colbase0 + ct * BN;

    f32x4 acc[2][8];
    #pragma unroll
    for (int mi = 0; mi < 2; ++mi)
      #pragma unroll
      for (int ni = 0; ni < 8; ++ni)
        acc[mi][ni] = (f32x4){0.f, 0.f, 0.f, 0.f};

    __syncthreads();
    // stage B tile (128 rows x 512 B). phys 16B-slot p holds logical kslot p^(row&31).
    #pragma unroll
    for (int it = 0; it < 16; ++it) {
      const int L   = it * 256 + tid;   // phys 16B-slot linear index
      const int row = L >> 5;           // 32 slots per row
      const int ks  = (L & 31) ^ (row & 31);
      const unsigned char* g = F + (size_t)(colbase + row) * 512 + ks * 16;
      __builtin_amdgcn_global_load_lds(
          (const __attribute__((address_space(1))) void*)g,
          (__attribute__((address_space(3))) void*)(Bs + L * 16), 16, 0, 0);
    }
    __syncthreads();

    #pragma unroll
    for (int k = 0; k < 16; ++k) {
      #pragma unroll
      for (int ni = 0; ni < 8; ++ni) {
        const int row = ni*16 + l15;
        const int g8  = k*4 + quad;                       // 8-byte group in row
        const int a   = row*512 + (((g8 >> 1) ^ (row & 31)) << 4) + (g8 & 1)*8;
        long b = *(const long*)(Bs + a);
        acc[0][ni] = __builtin_amdgcn_mfma_f32_16x16x32_fp8_fp8(af[0][k], b, acc[0][ni], 0, 0, 0);
        acc[1][ni] = __builtin_amdgcn_mfma_f32_16x16x32_fp8_fp8(af[1][k], b, acc[1][ni], 0, 0, 0);
      }
    }

    // epilogue: fold the 32x128 tile into per-row partial sums
    int tc[8];
    #pragma unroll
    for (int ni = 0; ni < 8; ++ni) tc[ni] = tgt[colbase + ni*16 + l15];
    #pragma unroll
    for (int mi = 0; mi < 2; ++mi)
      #pragma unroll
      for (int ni = 0; ni < 8; ++ni)
        #pragma unroll
        for (int r = 0; r < 4; ++r) {
          float v = acc[mi][ni][r];                 // raw dot in [-1,1]
          se[mi][r] += __builtin_amdgcn_exp2f(fmaf(v, C1, C0));
          if (tc[ni] == trow[mi][r]) ms[mi][r] += v;  // diagonal removed in kfinal
        }
  }

  // reduce across the 16 lanes of each quad (cols), write per-row partials
  #pragma unroll
  for (int mi = 0; mi < 2; ++mi)
    #pragma unroll
    for (int r = 0; r < 4; ++r) {
      float s = se[mi][r], m = ms[mi][r];
      #pragma unroll
      for (int off = 1; off < 16; off <<= 1) {
        s += __shfl_xor(s, off, 64);
        m += __shfl_xor(m, off, 64);
      }
      if (l15 == 0) {
        int row = rowbase + wave*32 + mi*16 + quad*4 + r;
        psum[(size_t)split * N + row]  = s;
        pmask[(size_t)split * N + row] = m;
      }
    }
}

// finalize: 32 blocks x 256 rows each; per-block histogram (targets are L2-hot),
// per-row term, wave reduce, one atomicAdd per block into pre-zeroed out.
__global__ __launch_bounds__(256) void kfinal(
    const float* __restrict__ psum, const float* __restrict__ pmask,
    const int* __restrict__ tgt, float* __restrict__ out, int N) {
  __shared__ int h[128];
  __shared__ float wsum[4];
  const int tid = threadIdx.x;
  if (tid < 128) h[tid] = 0;
  __syncthreads();
  for (int i = tid; i < N; i += 256) atomicAdd(&h[tgt[i] & 127], 1);
  __syncthreads();

  const int i = blockIdx.x * 256 + tid;
  float s = 0.f, m = 0.f;
  #pragma unroll
  for (int sp = 0; sp < NSPLIT; ++sp) {
    s += psum[(size_t)sp * N + i];
    m += pmask[(size_t)sp * N + i];
  }
  const float invT = 1.0f / TEMP;
  float cnt = (float)(h[tgt[i] & 127] - 1);
  // LSE_i = invT + log(s);  sum_mask sim = (m - selfdot(~1.0)) * invT
  float term = (m - 1.0f) * invT / cnt - (logf(s) + invT);
  #pragma unroll
  for (int off = 1; off < 64; off <<= 1) term += __shfl_xor(term, off, 64);
  if ((tid & 63) == 0) wsum[tid >> 6] = term;
  __syncthreads();
  if (tid == 0)
    atomicAdd(out, -(wsum[0] + wsum[1] + wsum[2] + wsum[3]) / (float)N);
}

extern "C" void kernel_launch(void* const* d_in, const int* in_sizes, int n_in,
                              void* d_out, int out_size, void* d_ws, size_t ws_size,
                              hipStream_t stream) {
  const float* X  = (const float*)d_in[0];
  const int* tgt  = (const int*)d_in[1];
  float* out      = (float*)d_out;
  const int N = in_sizes[1];
  const int D = in_sizes[0] / N;

  char* w = (char*)d_ws;
  unsigned char* Fq = (unsigned char*)w;
  size_t off = (size_t)N * D;                          // fp8: 1 B/elem
  float* psum  = (float*)(w + off); off += (size_t)NSPLIT * N * sizeof(float);
  float* pmask = (float*)(w + off);

  hipMemsetAsync(d_out, 0, sizeof(float), stream);
  knorm<<<N / 4, 256, 0, stream>>>(X, Fq, D);
  kmain<<<(N / BM) * NSPLIT, 256, 0, stream>>>(Fq, tgt, psum, pmask, N, D);
  kfinal<<<N / 256, 256, 0, stream>>>(psum, pmask, tgt, out, N);
}